// Round 14
// baseline (193.678 us; speedup 1.0000x reference)
//
#include <hip/hip_runtime.h>
#include <hip/hip_fp16.h>
#include <math.h>

#define GN    16384
#define MAXD  48
#define BN_SCALE 0.9999950000374998f   // 1/sqrt(1+1e-5)

typedef __attribute__((ext_vector_type(8))) short short8;
typedef __attribute__((ext_vector_type(4))) float f32x4;
typedef __attribute__((ext_vector_type(2))) float f32x2v;   // clang vector: ok for nontemporal builtins
typedef __attribute__((ext_vector_type(4))) float f32x4v;
typedef _Float16 __attribute__((ext_vector_type(2))) h2v;

__device__ inline short f2bf(float x) {
    unsigned u = __float_as_uint(x);
    return (short)((u + 0x7fffu + ((u >> 16) & 1u)) >> 16);
}
__device__ inline float bf2f(short s) {
    return __uint_as_float(((unsigned)(unsigned short)s) << 16);
}

struct F2 { float x, y; };
__device__ inline F2 f2min(F2 a, F2 b) { return {fminf(a.x, b.x), fminf(a.y, b.y)}; }
__device__ inline F2 f2max(F2 a, F2 b) { return {fmaxf(a.x, b.x), fmaxf(a.y, b.y)}; }

// ---- tracker state (4-deep min/max + sum), F2 = 2 features per lane ----
struct Trk {
    F2 tot, s0, s1, s2, s3, l0, l1, l2, l3;
};
__device__ inline void trk_init(Trk& T) {
    T.tot = {0.f, 0.f};
    T.s0 = T.s1 = T.s2 = T.s3 = { INFINITY,  INFINITY};
    T.l0 = T.l1 = T.l2 = T.l3 = {-INFINITY, -INFINITY};
}
// masked push: invalid elems are exact no-ops (sum+=0, min sees +INF, max sees -INF)
__device__ inline void trk_push_light(Trk& T, F2 x, bool valid) {
    F2 xs = {valid ? x.x :  INFINITY, valid ? x.y :  INFINITY};
    F2 xl = {valid ? x.x : -INFINITY, valid ? x.y : -INFINITY};
    T.tot.x += valid ? x.x : 0.f;
    T.tot.y += valid ? x.y : 0.f;
    T.s0 = f2min(T.s0, xs);
    T.l0 = f2max(T.l0, xl);
}
__device__ inline void trk_push_full(Trk& T, F2 x, bool valid) {
    F2 a = {valid ? x.x :  INFINITY, valid ? x.y :  INFINITY};
    F2 b = {valid ? x.x : -INFINITY, valid ? x.y : -INFINITY};
    T.tot.x += valid ? x.x : 0.f;
    T.tot.y += valid ? x.y : 0.f;
    F2 t0 = f2min(T.s0, a); a = f2max(T.s0, a); T.s0 = t0;
    F2 t1 = f2min(T.s1, a); a = f2max(T.s1, a); T.s1 = t1;
    F2 t2 = f2min(T.s2, a); a = f2max(T.s2, a); T.s2 = t2;
    T.s3 = f2min(T.s3, a);
    F2 u0 = f2max(T.l0, b); b = f2min(T.l0, b); T.l0 = u0;
    F2 u1 = f2max(T.l1, b); b = f2min(T.l1, b); T.l1 = u1;
    F2 u2 = f2max(T.l2, b); b = f2min(T.l2, b); T.l2 = u2;
    T.l3 = f2max(T.l3, b);
}
__device__ inline F2 trk_finish(const Trk& T, int cnt) {
    int t = (int)floorf((float)cnt * 0.1f);
    if (t < 1) t = 1;
    int tcnt = cnt - 2 * t;
    bool use_trim = (cnt >= 5) && (tcnt > 0);
    float dd = (float)cnt;
    F2 res;
    if (use_trim) {
        int tt = min(t, 4);
        F2 bot = T.s0, top = T.l0;
        if (tt > 1) { bot.x += T.s1.x; bot.y += T.s1.y; top.x += T.l1.x; top.y += T.l1.y; }
        if (tt > 2) { bot.x += T.s2.x; bot.y += T.s2.y; top.x += T.l2.x; top.y += T.l2.y; }
        if (tt > 3) { bot.x += T.s3.x; bot.y += T.s3.y; top.x += T.l3.x; top.y += T.l3.y; }
        float inv = 1.0f / (dd * (float)tcnt);
        res.x = (T.tot.x - bot.x - top.x) * inv;
        res.y = (T.tot.y - bot.y - top.y) * inv;
    } else {
        float inv = 1.0f / (dd * dd);
        res.x = T.tot.x * inv;
        res.y = T.tot.y * inv;
    }
    return res;
}

// ---------------------------------------------------------------------------
// Single-node trimmed mean (used by fused2), chunk-8 prefetch.
// ---------------------------------------------------------------------------
__device__ inline F2 trim_core(const _Float16* __restrict__ HL,
                               const int* __restrict__ srow, int cnt, int d, int f2i)
{
    Trk T; trk_init(T);
    bool light = (cnt < 20);
    for (int i = 0; i < d; i += 8) {
        h2v b[8];
        #pragma unroll
        for (int k = 0; k < 8; ++k) {
            int ia = min(i + k, d - 1);
            b[k] = *reinterpret_cast<const h2v*>(HL + srow[ia] + f2i);
        }
        if (light) {
            #pragma unroll
            for (int k = 0; k < 8; ++k)
                trk_push_light(T, {(float)b[k][0], (float)b[k][1]}, i + k < d);
        } else {
            #pragma unroll
            for (int k = 0; k < 8; ++k)
                trk_push_full(T, {(float)b[k][0], (float)b[k][1]}, i + k < d);
        }
    }
    return trk_finish(T, cnt);
}

// ---------------------------------------------------------------------------
// Dispatch 1: zero fill + split/swizzle W into MFMA B-fragment order.
// ---------------------------------------------------------------------------
__global__ __launch_bounds__(256) void k_prep(
    int* __restrict__ fill,
    const float* __restrict__ Wl0, const float* __restrict__ Wr0,
    const float* __restrict__ Wl1, const float* __restrict__ Wr1,
    short* __restrict__ W5)
{
    int t = blockIdx.x * 256 + threadIdx.x;   // 0..16383
    fill[t] = 0;

    int layer = t >> 13;
    int g     = t & 8191;
    int split = (g >> 12) & 1;
    int ks    = (g >> 10) & 3;
    int nt    = (g >> 6) & 15;
    int l     = g & 63;
    int q = l >> 4, r = l & 15;
    int n = nt * 16 + r;
    const float* W = (n < 128) ? (layer ? Wl1 : Wl0) : (layer ? Wr1 : Wr0);
    int ncol = n & 127;
    short8 o8;
    #pragma unroll
    for (int j = 0; j < 8; ++j) {
        int k = ks * 32 + (j >> 2) * 16 + q * 4 + (j & 3);
        float wv = W[k * 128 + ncol];
        short hi = f2bf(wv);
        o8[j] = split ? f2bf(wv - bf2f(hi)) : hi;
    }
    *reinterpret_cast<short8*>(W5 + ((size_t)layer * 8192 + g) * 8) = o8;
}

// ---------------------------------------------------------------------------
// GEMM quadrant (NT n-tiles of 16 cols): HL(fp16)=A@Wl+bl ; HR(f32)=A@Wr+br.
// HR stores are nontemporal (stream-once buffer; keep L2 for gathered HL).
// ---------------------------------------------------------------------------
template<int NT>
__device__ inline void gemm_tile_t(const short8 Ahi[4], const short8 Alo[4],
                                   const short* __restrict__ W5,
                                   const float* __restrict__ bl,
                                   const float* __restrict__ br,
                                   _Float16* __restrict__ HL, float* __restrict__ HR,
                                   int tile, int half, int ntg0, int q, int r, int l)
{
    f32x4 acc[NT];
    #pragma unroll
    for (int nt = 0; nt < NT; ++nt) {
        int ntg = ntg0 + nt;
        float b = (ntg < 8) ? bl[ntg * 16 + r] : br[(ntg - 8) * 16 + r];
        acc[nt] = (f32x4){b, b, b, b};
    }
    #pragma unroll
    for (int ks = 0; ks < 4; ++ks) {
        #pragma unroll
        for (int nt = 0; nt < NT; ++nt) {
            int ntg = ntg0 + nt;
            short8 Bhi = *reinterpret_cast<const short8*>(
                W5 + ((size_t)(ks * 16 + ntg) * 64 + l) * 8);
            short8 Blo = *reinterpret_cast<const short8*>(
                W5 + ((size_t)((4 + ks) * 16 + ntg) * 64 + l) * 8);
            acc[nt] = __builtin_amdgcn_mfma_f32_16x16x32_bf16(Ahi[ks], Bhi, acc[nt], 0, 0, 0);
            acc[nt] = __builtin_amdgcn_mfma_f32_16x16x32_bf16(Ahi[ks], Blo, acc[nt], 0, 0, 0);
            acc[nt] = __builtin_amdgcn_mfma_f32_16x16x32_bf16(Alo[ks], Bhi, acc[nt], 0, 0, 0);
        }
    }
    const int rb = tile * 32 + half * 16 + 4 * q;
    #pragma unroll
    for (int nt = 0; nt < NT; ++nt) {
        int ntg = ntg0 + nt;
        if (ntg < 8) {
            int c = ntg * 16 + r;
            #pragma unroll
            for (int j = 0; j < 4; ++j)
                HL[(size_t)(rb + j) * 128 + c] = (_Float16)acc[nt][j];
        } else {
            int c = (ntg - 8) * 16 + r;
            #pragma unroll
            for (int j = 0; j < 4; ++j)
                __builtin_nontemporal_store(acc[nt][j], &HR[(size_t)(rb + j) * 128 + c]);
        }
    }
}

// ---------------------------------------------------------------------------
// Dispatch 2 (512 thr): blocks [0,512) = GEMM layer 0 (8 waves, 16x64 each);
// blocks [512,576) = adjacency build (atomic append, order-invariant).
// ---------------------------------------------------------------------------
__global__ __launch_bounds__(512, 4) void k_fused0(
    const float* __restrict__ X, const int* __restrict__ ei, int E,
    int* __restrict__ adj, int* __restrict__ fill,
    const short* __restrict__ W5,
    const float* __restrict__ bl, const float* __restrict__ br,
    _Float16* __restrict__ HL, float* __restrict__ HR)
{
    const int tid = threadIdx.x;
    if (blockIdx.x >= 512) {          // ---- build ----
        const int* src = ei;
        const int* dst = ei + E;
        int g0 = (blockIdx.x - 512) * 512 + tid;
        for (int i = g0; i < E + GN; i += 64 * 512) {
            int s, dv;
            if (i < E) { s = src[i]; dv = dst[i]; }
            else       { s = i - E;  dv = i - E; }       // self loop
            int slot = atomicAdd(&fill[dv], 1);
            if (slot < MAXD) adj[dv * MAXD + slot] = s;  // drop overflow
        }
        return;
    }
    // ---- GEMM layer 0 ----
    const int w = tid >> 6, l = tid & 63;
    const int q = l >> 4, r = l & 15;
    const int half = w & 1, quarter = w >> 1;
    const int rowA = blockIdx.x * 32 + half * 16 + r;

    short8 Ahi[4], Alo[4];
    const f32x4v* xp = reinterpret_cast<const f32x4v*>(X + (size_t)rowA * 128);
    #pragma unroll
    for (int h = 0; h < 8; ++h) {
        f32x4v v = __builtin_nontemporal_load(xp + h * 4 + q);
        float xv[4] = {v.x, v.y, v.z, v.w};
        int ks = h >> 1, hk = h & 1;
        #pragma unroll
        for (int j = 0; j < 4; ++j) {
            short hi = f2bf(xv[j]);
            Ahi[ks][hk * 4 + j] = hi;
            Alo[ks][hk * 4 + j] = f2bf(xv[j] - bf2f(hi));
        }
    }
    gemm_tile_t<4>(Ahi, Alo, W5, bl, br, HL, HR, blockIdx.x, half, quarter * 4, q, r, l);
}

// ---------------------------------------------------------------------------
// Dispatch 3 (512 thr, 8 waves): fused agg(layer0)+BN+ReLU -> LDS -> GEMM L1.
// Wave w aggregates nodes w*4..w*4+3 as TWO INTERLEAVED PAIRS (16 loads in
// flight), then GEMMs a 16x64 quadrant.
// ---------------------------------------------------------------------------
__global__ __launch_bounds__(512, 4) void k_fused1(
    const _Float16* __restrict__ HL0, const float* __restrict__ HR0,
    const int* __restrict__ adj, const int* __restrict__ fill,
    const float* __restrict__ g, const float* __restrict__ be,
    const short* __restrict__ W5,
    const float* __restrict__ bl, const float* __restrict__ br,
    _Float16* __restrict__ HL1, float* __restrict__ HR1)
{
    __shared__ float hbs[32][132];       // +4 pad
    __shared__ int sadj[8][2][MAXD];
    const int tid = threadIdx.x, w = tid >> 6, l = tid & 63;
    const int f2i = l * 2;
    const int v0 = blockIdx.x * 32;
    const float gs0 = BN_SCALE * g[f2i], gs1 = BN_SCALE * g[f2i + 1];
    const float be0 = be[f2i], be1 = be[f2i + 1];

    // ---- aggregate 4 nodes per wave, 2 at a time (interleaved) ----
    for (int p = 0; p < 2; ++p) {
        const int vA = v0 + w * 4 + p * 2;
        const int vB = vA + 1;
        const int cA = fill[vA], cB = fill[vB];
        const int dA = min(cA, MAXD), dB = min(cB, MAXD);
        if (l < dA) sadj[w][0][l] = adj[vA * MAXD + l] * 128;   // wave-private
        if (l < dB) sadj[w][1][l] = adj[vB * MAXD + l] * 128;

        Trk TA, TB;
        trk_init(TA); trk_init(TB);
        const bool light = (cA < 20) && (cB < 20);
        const int dmax = max(dA, dB);
        for (int i = 0; i < dmax; i += 8) {
            h2v bA[8], bB[8];
            #pragma unroll
            for (int k = 0; k < 8; ++k) {
                int iaA = min(i + k, dA - 1);
                int iaB = min(i + k, dB - 1);
                bA[k] = *reinterpret_cast<const h2v*>(HL0 + sadj[w][0][iaA] + f2i);
                bB[k] = *reinterpret_cast<const h2v*>(HL0 + sadj[w][1][iaB] + f2i);
            }
            if (light) {
                #pragma unroll
                for (int k = 0; k < 8; ++k) {
                    trk_push_light(TA, {(float)bA[k][0], (float)bA[k][1]}, i + k < dA);
                    trk_push_light(TB, {(float)bB[k][0], (float)bB[k][1]}, i + k < dB);
                }
            } else {
                #pragma unroll
                for (int k = 0; k < 8; ++k) {
                    trk_push_full(TA, {(float)bA[k][0], (float)bA[k][1]}, i + k < dA);
                    trk_push_full(TB, {(float)bB[k][0], (float)bB[k][1]}, i + k < dB);
                }
            }
        }
        F2 rA = trk_finish(TA, cA);
        F2 rB = trk_finish(TB, cB);
        const f32x2v hrA = __builtin_nontemporal_load(
            reinterpret_cast<const f32x2v*>(HR0 + (size_t)vA * 128 + f2i));
        const f32x2v hrB = __builtin_nontemporal_load(
            reinterpret_cast<const f32x2v*>(HR0 + (size_t)vB * 128 + f2i));
        hbs[w * 4 + p * 2][f2i]         = fmaxf((rA.x + hrA.x) * gs0 + be0, 0.f);
        hbs[w * 4 + p * 2][f2i + 1]     = fmaxf((rA.y + hrA.y) * gs1 + be1, 0.f);
        hbs[w * 4 + p * 2 + 1][f2i]     = fmaxf((rB.x + hrB.x) * gs0 + be0, 0.f);
        hbs[w * 4 + p * 2 + 1][f2i + 1] = fmaxf((rB.y + hrB.y) * gs1 + be1, 0.f);
    }
    __syncthreads();

    // ---- GEMM layer 1 from LDS ----
    const int q = l >> 4, r = l & 15;
    const int half = w & 1, quarter = w >> 1;
    const int m = half * 16 + r;
    short8 Ahi[4], Alo[4];
    #pragma unroll
    for (int h = 0; h < 8; ++h) {
        float4 vv = *reinterpret_cast<const float4*>(&hbs[m][h * 16 + 4 * q]);
        float xv[4] = {vv.x, vv.y, vv.z, vv.w};
        int ks = h >> 1, hk = h & 1;
        #pragma unroll
        for (int j = 0; j < 4; ++j) {
            short hi = f2bf(xv[j]);
            Ahi[ks][hk * 4 + j] = hi;
            Alo[ks][hk * 4 + j] = f2bf(xv[j] - bf2f(hi));
        }
    }
    gemm_tile_t<4>(Ahi, Alo, W5, bl, br, HL1, HR1, blockIdx.x, half, quarter * 4, q, r, l);
}

// ---------------------------------------------------------------------------
// Dispatch 4: fused agg(layer1)+BN+ReLU + output GEMM (128->2, wave reduce).
// ---------------------------------------------------------------------------
__global__ __launch_bounds__(256) void k_fused2(
    const _Float16* __restrict__ HL1, const float* __restrict__ HR1,
    const int* __restrict__ adj, const int* __restrict__ fill,
    const float* __restrict__ g, const float* __restrict__ be,
    const float* __restrict__ Wl2, const float* __restrict__ bl2,
    const float* __restrict__ Wr2, const float* __restrict__ br2,
    float* __restrict__ hl2, float* __restrict__ hr2)
{
    __shared__ int sadj[4][MAXD];
    const int tid = threadIdx.x, w = tid >> 6, l = tid & 63;
    const int f2i = l * 2;
    const int v = blockIdx.x * 4 + w;
    const int cnt = fill[v];
    const int d = min(cnt, MAXD);
    if (l < d) sadj[w][l] = adj[v * MAXD + l] * 128;
    F2 res = trim_core(HL1, sadj[w], cnt, d, f2i);
    const f32x2v hrv = __builtin_nontemporal_load(
        reinterpret_cast<const f32x2v*>(HR1 + (size_t)v * 128 + f2i));
    float h0 = fmaxf((res.x + hrv.x) * (BN_SCALE * g[f2i])     + be[f2i],     0.f);
    float h1 = fmaxf((res.y + hrv.y) * (BN_SCALE * g[f2i + 1]) + be[f2i + 1], 0.f);

    float4 wl = *reinterpret_cast<const float4*>(Wl2 + l * 4);
    float4 wr = *reinterpret_cast<const float4*>(Wr2 + l * 4);
    float p0 = h0 * wl.x + h1 * wl.z;
    float p1 = h0 * wl.y + h1 * wl.w;
    float p2 = h0 * wr.x + h1 * wr.z;
    float p3 = h0 * wr.y + h1 * wr.w;
    #pragma unroll
    for (int off = 1; off < 64; off <<= 1) {
        p0 += __shfl_xor(p0, off);
        p1 += __shfl_xor(p1, off);
        p2 += __shfl_xor(p2, off);
        p3 += __shfl_xor(p3, off);
    }
    if (l == 0) {
        hl2[v * 2 + 0] = p0 + bl2[0];
        hl2[v * 2 + 1] = p1 + bl2[1];
        hr2[v * 2 + 0] = p2 + br2[0];
        hr2[v * 2 + 1] = p3 + br2[1];
    }
}

// ---------------------------------------------------------------------------
// Dispatch 5: final trimmed aggregation over 2 features (chunk-prefetched).
// ---------------------------------------------------------------------------
__global__ __launch_bounds__(256) void k_agg_out(
    const float* __restrict__ hl2, const float* __restrict__ hr2,
    const int* __restrict__ adj, const int* __restrict__ fill,
    float* __restrict__ out)
{
    int idx = blockIdx.x * 256 + threadIdx.x;
    int v = idx >> 1, j = idx & 1;
    int cnt = fill[v];
    int d = min(cnt, MAXD);
    const int* ap = adj + v * MAXD;

    float total = 0.f;
    float s0 = INFINITY, s1 = INFINITY, s2 = INFINITY, s3 = INFINITY;
    float l0 = -INFINITY, l1 = -INFINITY, l2 = -INFINITY, l3 = -INFINITY;
    for (int i = 0; i < d; i += 8) {
        float b[8];
        bool val[8];
        #pragma unroll
        for (int k = 0; k < 8; ++k) {
            int ia = min(i + k, d - 1);
            b[k] = hl2[ap[ia] * 2 + j];
            val[k] = (i + k) < d;
        }
        #pragma unroll
        for (int k = 0; k < 8; ++k) {
            float xs = val[k] ? b[k] :  INFINITY;
            float xl = val[k] ? b[k] : -INFINITY;
            total += val[k] ? b[k] : 0.f;
            float a = xs;
            float t0 = fminf(s0, a); a = fmaxf(s0, a); s0 = t0;
            float t1 = fminf(s1, a); a = fmaxf(s1, a); s1 = t1;
            float t2 = fminf(s2, a); a = fmaxf(s2, a); s2 = t2;
            s3 = fminf(s3, a);
            float bb = xl;
            float u0 = fmaxf(l0, bb); bb = fminf(l0, bb); l0 = u0;
            float u1 = fmaxf(l1, bb); bb = fminf(l1, bb); l1 = u1;
            float u2 = fmaxf(l2, bb); bb = fminf(l2, bb); l2 = u2;
            l3 = fmaxf(l3, bb);
        }
    }

    int t = (int)floorf((float)cnt * 0.1f);
    if (t < 1) t = 1;
    int tcnt = cnt - 2 * t;
    bool use_trim = (cnt >= 5) && (tcnt > 0);
    float dd = (float)cnt;
    float res;
    if (use_trim) {
        int tt = min(t, 4);
        float bot = s0, top = l0;
        if (tt > 1) { bot += s1; top += l1; }
        if (tt > 2) { bot += s2; top += l2; }
        if (tt > 3) { bot += s3; top += l3; }
        res = (total - bot - top) / (dd * (float)tcnt);
    } else {
        res = total / (dd * dd);
    }
    out[idx] = res + hr2[idx];
}

// ---------------------------------------------------------------------------
extern "C" void kernel_launch(void* const* d_in, const int* in_sizes, int n_in,
                              void* d_out, int out_size, void* d_ws, size_t ws_size,
                              hipStream_t stream)
{
    const float* x   = (const float*)d_in[0];
    const int*   ei  = (const int*)d_in[1];
    const int    E   = in_sizes[1] / 2;
    const float* Wl0 = (const float*)d_in[2];
    const float* bl0 = (const float*)d_in[3];
    const float* Wr0 = (const float*)d_in[4];
    const float* br0 = (const float*)d_in[5];
    const float* g0  = (const float*)d_in[6];
    const float* be0 = (const float*)d_in[7];
    const float* Wl1 = (const float*)d_in[8];
    const float* bl1 = (const float*)d_in[9];
    const float* Wr1 = (const float*)d_in[10];
    const float* br1 = (const float*)d_in[11];
    const float* g1  = (const float*)d_in[12];
    const float* be1 = (const float*)d_in[13];
    const float* Wl2 = (const float*)d_in[14];
    const float* bl2 = (const float*)d_in[15];
    const float* Wr2 = (const float*)d_in[16];
    const float* br2 = (const float*)d_in[17];
    float* out = (float*)d_out;

    char* w = (char*)d_ws;
    int*      adj  = (int*)w;       w += (size_t)GN * MAXD * 4;
    int*      fill = (int*)w;       w += (size_t)GN * 4;
    _Float16* HL0  = (_Float16*)w;  w += (size_t)GN * 128 * 2;
    float*    HR0  = (float*)w;     w += (size_t)GN * 128 * 4;
    _Float16* HL1  = (_Float16*)w;  w += (size_t)GN * 128 * 2;
    float*    HR1  = (float*)w;     w += (size_t)GN * 128 * 4;
    short*    W5   = (short*)w;     w += (size_t)2 * 8192 * 16;
    float*    hl2  = (float*)w;     w += (size_t)GN * 2 * 4;
    float*    hr2  = (float*)w;     w += (size_t)GN * 2 * 4;

    k_prep  <<<GN / 256, 256, 0, stream>>>(fill, Wl0, Wr0, Wl1, Wr1, W5);
    k_fused0<<<576, 512, 0, stream>>>(x, ei, E, adj, fill, W5, bl0, br0, HL0, HR0);
    k_fused1<<<GN / 32, 512, 0, stream>>>(HL0, HR0, adj, fill, g0, be0,
                                          W5 + (size_t)8192 * 8, bl1, br1, HL1, HR1);
    k_fused2<<<GN / 4, 256, 0, stream>>>(HL1, HR1, adj, fill, g1, be1,
                                         Wl2, bl2, Wr2, br2, hl2, hr2);
    k_agg_out<<<GN * 2 / 256, 256, 0, stream>>>(hl2, hr2, adj, fill, out);
}

// Round 15
// 177.096 us; speedup vs baseline: 1.0936x; 1.0936x over previous
//
#include <hip/hip_runtime.h>
#include <hip/hip_fp16.h>
#include <math.h>

#define GN    16384
#define MAXD  48
#define BN_SCALE 0.9999950000374998f   // 1/sqrt(1+1e-5)

typedef __attribute__((ext_vector_type(8))) short short8;
typedef __attribute__((ext_vector_type(4))) float f32x4;
typedef _Float16 __attribute__((ext_vector_type(2))) h2v;

__device__ inline short f2bf(float x) {
    unsigned u = __float_as_uint(x);
    return (short)((u + 0x7fffu + ((u >> 16) & 1u)) >> 16);
}
__device__ inline float bf2f(short s) {
    return __uint_as_float(((unsigned)(unsigned short)s) << 16);
}

struct F2 { float x, y; };
__device__ inline F2 f2min(F2 a, F2 b) { return {fminf(a.x, b.x), fminf(a.y, b.y)}; }
__device__ inline F2 f2max(F2 a, F2 b) { return {fmaxf(a.x, b.x), fmaxf(a.y, b.y)}; }

// ---- tracker: sum + up-to-4-deep min/max, 2 features (F2) per lane ----
struct Trk {
    F2 tot, s0, s1, s2, s3, l0, l1, l2, l3;
};
__device__ inline void trk_init(Trk& T) {
    T.tot = {0.f, 0.f};
    T.s0 = T.s1 = T.s2 = T.s3 = { INFINITY,  INFINITY};
    T.l0 = T.l1 = T.l2 = T.l3 = {-INFINITY, -INFINITY};
}
// depth-1 (t==1): min/max only
__device__ inline void push1(Trk& T, F2 x) {
    T.tot.x += x.x; T.tot.y += x.y;
    T.s0 = f2min(T.s0, x);
    T.l0 = f2max(T.l0, x);
}
// depth-2 (t==2)
__device__ inline void push2(Trk& T, F2 x) {
    T.tot.x += x.x; T.tot.y += x.y;
    F2 a = x;
    F2 t0 = f2min(T.s0, a); a = f2max(T.s0, a); T.s0 = t0;
    T.s1 = f2min(T.s1, a);
    F2 b = x;
    F2 u0 = f2max(T.l0, b); b = f2min(T.l0, b); T.l0 = u0;
    T.l1 = f2max(T.l1, b);
}
// depth-4 (t>=3, rare)
__device__ inline void push4(Trk& T, F2 x) {
    T.tot.x += x.x; T.tot.y += x.y;
    F2 a = x;
    F2 t0 = f2min(T.s0, a); a = f2max(T.s0, a); T.s0 = t0;
    F2 t1 = f2min(T.s1, a); a = f2max(T.s1, a); T.s1 = t1;
    F2 t2 = f2min(T.s2, a); a = f2max(T.s2, a); T.s2 = t2;
    T.s3 = f2min(T.s3, a);
    F2 b = x;
    F2 u0 = f2max(T.l0, b); b = f2min(T.l0, b); T.l0 = u0;
    F2 u1 = f2max(T.l1, b); b = f2min(T.l1, b); T.l1 = u1;
    F2 u2 = f2max(T.l2, b); b = f2min(T.l2, b); T.l2 = u2;
    T.l3 = f2max(T.l3, b);
}
__device__ inline F2 trk_finish(const Trk& T, int cnt) {
    int t = (int)floorf((float)cnt * 0.1f);
    if (t < 1) t = 1;
    int tcnt = cnt - 2 * t;
    bool use_trim = (cnt >= 5) && (tcnt > 0);
    float dd = (float)cnt;
    F2 res;
    if (use_trim) {
        int tt = min(t, 4);
        F2 bot = T.s0, top = T.l0;
        if (tt > 1) { bot.x += T.s1.x; bot.y += T.s1.y; top.x += T.l1.x; top.y += T.l1.y; }
        if (tt > 2) { bot.x += T.s2.x; bot.y += T.s2.y; top.x += T.l2.x; top.y += T.l2.y; }
        if (tt > 3) { bot.x += T.s3.x; bot.y += T.s3.y; top.x += T.l3.x; top.y += T.l3.y; }
        float inv = 1.0f / (dd * (float)tcnt);
        res.x = (T.tot.x - bot.x - top.x) * inv;
        res.y = (T.tot.y - bot.y - top.y) * inv;
    } else {
        float inv = 1.0f / (dd * dd);
        res.x = T.tot.x * inv;
        res.y = T.tot.y * inv;
    }
    return res;
}

// ---------------------------------------------------------------------------
// Wave-uniform trimmed mean via register adjacency + readlane scalar-base
// gathers. adjb: lane l holds byte-offset (row*256) of adj elem min(l,d-1).
// f2i2 = byte offset of this lane's feature pair. All VALU-lean:
// gather = v_readlane (uniform base) + global_load saddr.
// ---------------------------------------------------------------------------
__device__ inline F2 trim_core_reg(const _Float16* __restrict__ HL,
                                   int adjb, int cnt, int d, int f2i2)
{
    const char* HLc = (const char*)HL;
    Trk T; trk_init(T);
    const int mode = (cnt < 20) ? 0 : ((cnt < 30) ? 1 : 2);

    int i = 0;
    for (; i + 8 <= d; i += 8) {          // full chunks: no masking
        h2v b[8];
        #pragma unroll
        for (int k = 0; k < 8; ++k) {
            int sofs = __builtin_amdgcn_readlane(adjb, i + k);
            b[k] = *reinterpret_cast<const h2v*>(HLc + sofs + f2i2);
        }
        if (mode == 0) {
            #pragma unroll
            for (int k = 0; k < 8; ++k) push1(T, {(float)b[k][0], (float)b[k][1]});
        } else if (mode == 1) {
            #pragma unroll
            for (int k = 0; k < 8; ++k) push2(T, {(float)b[k][0], (float)b[k][1]});
        } else {
            #pragma unroll
            for (int k = 0; k < 8; ++k) push4(T, {(float)b[k][0], (float)b[k][1]});
        }
    }
    if (i < d) {                           // one masked tail chunk
        h2v b[8];
        #pragma unroll
        for (int k = 0; k < 8; ++k) {
            int ia = min(i + k, d - 1);    // scalar clamp
            int sofs = __builtin_amdgcn_readlane(adjb, ia);
            b[k] = *reinterpret_cast<const h2v*>(HLc + sofs + f2i2);
        }
        #pragma unroll
        for (int k = 0; k < 8; ++k) {
            bool vld = (i + k) < d;
            F2 x = {vld ? (float)b[k][0] : 0.f, vld ? (float)b[k][1] : 0.f};
            F2 xs = {vld ? x.x :  INFINITY, vld ? x.y :  INFINITY};
            F2 xl = {vld ? x.x : -INFINITY, vld ? x.y : -INFINITY};
            T.tot.x += x.x; T.tot.y += x.y;
            if (mode == 0) {
                T.s0 = f2min(T.s0, xs);
                T.l0 = f2max(T.l0, xl);
            } else if (mode == 1) {
                F2 a = xs;
                F2 t0 = f2min(T.s0, a); a = f2max(T.s0, a); T.s0 = t0;
                T.s1 = f2min(T.s1, a);
                F2 bb = xl;
                F2 u0 = f2max(T.l0, bb); bb = f2min(T.l0, bb); T.l0 = u0;
                T.l1 = f2max(T.l1, bb);
            } else {
                F2 a = xs;
                F2 t0 = f2min(T.s0, a); a = f2max(T.s0, a); T.s0 = t0;
                F2 t1 = f2min(T.s1, a); a = f2max(T.s1, a); T.s1 = t1;
                F2 t2 = f2min(T.s2, a); a = f2max(T.s2, a); T.s2 = t2;
                T.s3 = f2min(T.s3, a);
                F2 bb = xl;
                F2 u0 = f2max(T.l0, bb); bb = f2min(T.l0, bb); T.l0 = u0;
                F2 u1 = f2max(T.l1, bb); bb = f2min(T.l1, bb); T.l1 = u1;
                F2 u2 = f2max(T.l2, bb); bb = f2min(T.l2, bb); T.l2 = u2;
                T.l3 = f2max(T.l3, bb);
            }
        }
    }
    return trk_finish(T, cnt);
}

// ---------------------------------------------------------------------------
// Dispatch 1: zero fill + split/swizzle W into MFMA B-fragment order.
// ---------------------------------------------------------------------------
__global__ __launch_bounds__(256) void k_prep(
    int* __restrict__ fill,
    const float* __restrict__ Wl0, const float* __restrict__ Wr0,
    const float* __restrict__ Wl1, const float* __restrict__ Wr1,
    short* __restrict__ W5)
{
    int t = blockIdx.x * 256 + threadIdx.x;   // 0..16383
    fill[t] = 0;

    int layer = t >> 13;
    int g     = t & 8191;
    int split = (g >> 12) & 1;
    int ks    = (g >> 10) & 3;
    int nt    = (g >> 6) & 15;
    int l     = g & 63;
    int q = l >> 4, r = l & 15;
    int n = nt * 16 + r;
    const float* W = (n < 128) ? (layer ? Wl1 : Wl0) : (layer ? Wr1 : Wr0);
    int ncol = n & 127;
    short8 o8;
    #pragma unroll
    for (int j = 0; j < 8; ++j) {
        int k = ks * 32 + (j >> 2) * 16 + q * 4 + (j & 3);
        float wv = W[k * 128 + ncol];
        short hi = f2bf(wv);
        o8[j] = split ? f2bf(wv - bf2f(hi)) : hi;
    }
    *reinterpret_cast<short8*>(W5 + ((size_t)layer * 8192 + g) * 8) = o8;
}

// ---------------------------------------------------------------------------
// GEMM quadrant (NT n-tiles of 16 cols): HL(fp16)=A@Wl+bl ; HR(f32)=A@Wr+br.
// ---------------------------------------------------------------------------
template<int NT>
__device__ inline void gemm_tile_t(const short8 Ahi[4], const short8 Alo[4],
                                   const short* __restrict__ W5,
                                   const float* __restrict__ bl,
                                   const float* __restrict__ br,
                                   _Float16* __restrict__ HL, float* __restrict__ HR,
                                   int tile, int half, int ntg0, int q, int r, int l)
{
    f32x4 acc[NT];
    #pragma unroll
    for (int nt = 0; nt < NT; ++nt) {
        int ntg = ntg0 + nt;
        float b = (ntg < 8) ? bl[ntg * 16 + r] : br[(ntg - 8) * 16 + r];
        acc[nt] = (f32x4){b, b, b, b};
    }
    #pragma unroll
    for (int ks = 0; ks < 4; ++ks) {
        #pragma unroll
        for (int nt = 0; nt < NT; ++nt) {
            int ntg = ntg0 + nt;
            short8 Bhi = *reinterpret_cast<const short8*>(
                W5 + ((size_t)(ks * 16 + ntg) * 64 + l) * 8);
            short8 Blo = *reinterpret_cast<const short8*>(
                W5 + ((size_t)((4 + ks) * 16 + ntg) * 64 + l) * 8);
            acc[nt] = __builtin_amdgcn_mfma_f32_16x16x32_bf16(Ahi[ks], Bhi, acc[nt], 0, 0, 0);
            acc[nt] = __builtin_amdgcn_mfma_f32_16x16x32_bf16(Ahi[ks], Blo, acc[nt], 0, 0, 0);
            acc[nt] = __builtin_amdgcn_mfma_f32_16x16x32_bf16(Alo[ks], Bhi, acc[nt], 0, 0, 0);
        }
    }
    const int rb = tile * 32 + half * 16 + 4 * q;
    #pragma unroll
    for (int nt = 0; nt < NT; ++nt) {
        int ntg = ntg0 + nt;
        if (ntg < 8) {
            int c = ntg * 16 + r;
            #pragma unroll
            for (int j = 0; j < 4; ++j)
                HL[(size_t)(rb + j) * 128 + c] = (_Float16)acc[nt][j];
        } else {
            int c = (ntg - 8) * 16 + r;
            #pragma unroll
            for (int j = 0; j < 4; ++j)
                HR[(size_t)(rb + j) * 128 + c] = acc[nt][j];
        }
    }
}

// ---------------------------------------------------------------------------
// Dispatch 2 (512 thr): blocks [0,512) = GEMM layer 0 (8 waves, 16x64 each);
// blocks [512,576) = adjacency build (atomic append, order-invariant).
// ---------------------------------------------------------------------------
__global__ __launch_bounds__(512, 4) void k_fused0(
    const float* __restrict__ X, const int* __restrict__ ei, int E,
    int* __restrict__ adj, int* __restrict__ fill,
    const short* __restrict__ W5,
    const float* __restrict__ bl, const float* __restrict__ br,
    _Float16* __restrict__ HL, float* __restrict__ HR)
{
    const int tid = threadIdx.x;
    if (blockIdx.x >= 512) {          // ---- build ----
        const int* src = ei;
        const int* dst = ei + E;
        int g0 = (blockIdx.x - 512) * 512 + tid;
        for (int i = g0; i < E + GN; i += 64 * 512) {
            int s, dv;
            if (i < E) { s = src[i]; dv = dst[i]; }
            else       { s = i - E;  dv = i - E; }       // self loop
            int slot = atomicAdd(&fill[dv], 1);
            if (slot < MAXD) adj[dv * MAXD + slot] = s;  // drop overflow
        }
        return;
    }
    // ---- GEMM layer 0 ----
    const int w = tid >> 6, l = tid & 63;
    const int q = l >> 4, r = l & 15;
    const int half = w & 1, quarter = w >> 1;
    const int rowA = blockIdx.x * 32 + half * 16 + r;

    short8 Ahi[4], Alo[4];
    const float4* xp = reinterpret_cast<const float4*>(X + (size_t)rowA * 128);
    #pragma unroll
    for (int h = 0; h < 8; ++h) {
        float4 v = xp[h * 4 + q];
        float xv[4] = {v.x, v.y, v.z, v.w};
        int ks = h >> 1, hk = h & 1;
        #pragma unroll
        for (int j = 0; j < 4; ++j) {
            short hi = f2bf(xv[j]);
            Ahi[ks][hk * 4 + j] = hi;
            Alo[ks][hk * 4 + j] = f2bf(xv[j] - bf2f(hi));
        }
    }
    gemm_tile_t<4>(Ahi, Alo, W5, bl, br, HL, HR, blockIdx.x, half, quarter * 4, q, r, l);
}

// ---------------------------------------------------------------------------
// Dispatch 3 (512 thr, 8 waves): fused agg(layer0)+BN+ReLU -> LDS -> GEMM L1.
// Wave w aggregates nodes w*4..w*4+3 (register adjacency, readlane gathers),
// then GEMMs a 16x64 quadrant.
// ---------------------------------------------------------------------------
__global__ __launch_bounds__(512, 4) void k_fused1(
    const _Float16* __restrict__ HL0, const float* __restrict__ HR0,
    const int* __restrict__ adj, const int* __restrict__ fill,
    const float* __restrict__ g, const float* __restrict__ be,
    const short* __restrict__ W5,
    const float* __restrict__ bl, const float* __restrict__ br,
    _Float16* __restrict__ HL1, float* __restrict__ HR1)
{
    __shared__ float hbs[32][132];       // +4 pad
    const int tid = threadIdx.x, w = tid >> 6, l = tid & 63;
    const int f2i = l * 2;
    const int f2i2 = f2i * 2;            // byte offset into fp16 row
    const int v0 = blockIdx.x * 32;
    const float gs0 = BN_SCALE * g[f2i], gs1 = BN_SCALE * g[f2i + 1];
    const float be0 = be[f2i], be1 = be[f2i + 1];

    #pragma unroll
    for (int s = 0; s < 4; ++s) {
        const int v = v0 + w * 4 + s;
        const int cnt = fill[v];
        const int d = min(cnt, MAXD);
        const int adjb = adj[v * MAXD + min(l, d - 1)] << 8;   // row byte offset
        F2 res = trim_core_reg(HL0, adjb, cnt, d, f2i2);
        const float2 hrv = *reinterpret_cast<const float2*>(HR0 + (size_t)v * 128 + f2i);
        hbs[w * 4 + s][f2i]     = fmaxf((res.x + hrv.x) * gs0 + be0, 0.f);
        hbs[w * 4 + s][f2i + 1] = fmaxf((res.y + hrv.y) * gs1 + be1, 0.f);
    }
    __syncthreads();

    // ---- GEMM layer 1 from LDS ----
    const int q = l >> 4, r = l & 15;
    const int half = w & 1, quarter = w >> 1;
    const int m = half * 16 + r;
    short8 Ahi[4], Alo[4];
    #pragma unroll
    for (int h = 0; h < 8; ++h) {
        float4 vv = *reinterpret_cast<const float4*>(&hbs[m][h * 16 + 4 * q]);
        float xv[4] = {vv.x, vv.y, vv.z, vv.w};
        int ks = h >> 1, hk = h & 1;
        #pragma unroll
        for (int j = 0; j < 4; ++j) {
            short hi = f2bf(xv[j]);
            Ahi[ks][hk * 4 + j] = hi;
            Alo[ks][hk * 4 + j] = f2bf(xv[j] - bf2f(hi));
        }
    }
    gemm_tile_t<4>(Ahi, Alo, W5, bl, br, HL1, HR1, blockIdx.x, half, quarter * 4, q, r, l);
}

// ---------------------------------------------------------------------------
// Dispatch 4: fused agg(layer1)+BN+ReLU + output GEMM (128->2, wave reduce).
// ---------------------------------------------------------------------------
__global__ __launch_bounds__(256) void k_fused2(
    const _Float16* __restrict__ HL1, const float* __restrict__ HR1,
    const int* __restrict__ adj, const int* __restrict__ fill,
    const float* __restrict__ g, const float* __restrict__ be,
    const float* __restrict__ Wl2, const float* __restrict__ bl2,
    const float* __restrict__ Wr2, const float* __restrict__ br2,
    float* __restrict__ hl2, float* __restrict__ hr2)
{
    const int tid = threadIdx.x, w = tid >> 6, l = tid & 63;
    const int f2i = l * 2;
    const int f2i2 = f2i * 2;
    const int v = blockIdx.x * 4 + w;
    const int cnt = fill[v];
    const int d = min(cnt, MAXD);
    const int adjb = adj[v * MAXD + min(l, d - 1)] << 8;
    F2 res = trim_core_reg(HL1, adjb, cnt, d, f2i2);
    const float2 hrv = *reinterpret_cast<const float2*>(HR1 + (size_t)v * 128 + f2i);
    float h0 = fmaxf((res.x + hrv.x) * (BN_SCALE * g[f2i])     + be[f2i],     0.f);
    float h1 = fmaxf((res.y + hrv.y) * (BN_SCALE * g[f2i + 1]) + be[f2i + 1], 0.f);

    float4 wl = *reinterpret_cast<const float4*>(Wl2 + l * 4);
    float4 wr = *reinterpret_cast<const float4*>(Wr2 + l * 4);
    float p0 = h0 * wl.x + h1 * wl.z;
    float p1 = h0 * wl.y + h1 * wl.w;
    float p2 = h0 * wr.x + h1 * wr.z;
    float p3 = h0 * wr.y + h1 * wr.w;
    #pragma unroll
    for (int off = 1; off < 64; off <<= 1) {
        p0 += __shfl_xor(p0, off);
        p1 += __shfl_xor(p1, off);
        p2 += __shfl_xor(p2, off);
        p3 += __shfl_xor(p3, off);
    }
    if (l == 0) {
        hl2[v * 2 + 0] = p0 + bl2[0];
        hl2[v * 2 + 1] = p1 + bl2[1];
        hr2[v * 2 + 0] = p2 + br2[0];
        hr2[v * 2 + 1] = p3 + br2[1];
    }
}

// ---------------------------------------------------------------------------
// Dispatch 5: final trimmed aggregation over 2 features (chunk-prefetched).
// ---------------------------------------------------------------------------
__global__ __launch_bounds__(256) void k_agg_out(
    const float* __restrict__ hl2, const float* __restrict__ hr2,
    const int* __restrict__ adj, const int* __restrict__ fill,
    float* __restrict__ out)
{
    int idx = blockIdx.x * 256 + threadIdx.x;
    int v = idx >> 1, j = idx & 1;
    int cnt = fill[v];
    int d = min(cnt, MAXD);
    const int* ap = adj + v * MAXD;

    float total = 0.f;
    float s0 = INFINITY, s1 = INFINITY, s2 = INFINITY, s3 = INFINITY;
    float l0 = -INFINITY, l1 = -INFINITY, l2 = -INFINITY, l3 = -INFINITY;
    for (int i = 0; i < d; i += 8) {
        float b[8];
        bool val[8];
        #pragma unroll
        for (int k = 0; k < 8; ++k) {
            int ia = min(i + k, d - 1);
            b[k] = hl2[ap[ia] * 2 + j];
            val[k] = (i + k) < d;
        }
        #pragma unroll
        for (int k = 0; k < 8; ++k) {
            float xs = val[k] ? b[k] :  INFINITY;
            float xl = val[k] ? b[k] : -INFINITY;
            total += val[k] ? b[k] : 0.f;
            float a = xs;
            float t0 = fminf(s0, a); a = fmaxf(s0, a); s0 = t0;
            float t1 = fminf(s1, a); a = fmaxf(s1, a); s1 = t1;
            float t2 = fminf(s2, a); a = fmaxf(s2, a); s2 = t2;
            s3 = fminf(s3, a);
            float bb = xl;
            float u0 = fmaxf(l0, bb); bb = fminf(l0, bb); l0 = u0;
            float u1 = fmaxf(l1, bb); bb = fminf(l1, bb); l1 = u1;
            float u2 = fmaxf(l2, bb); bb = fminf(l2, bb); l2 = u2;
            l3 = fmaxf(l3, bb);
        }
    }

    int t = (int)floorf((float)cnt * 0.1f);
    if (t < 1) t = 1;
    int tcnt = cnt - 2 * t;
    bool use_trim = (cnt >= 5) && (tcnt > 0);
    float dd = (float)cnt;
    float res;
    if (use_trim) {
        int tt = min(t, 4);
        float bot = s0, top = l0;
        if (tt > 1) { bot += s1; top += l1; }
        if (tt > 2) { bot += s2; top += l2; }
        if (tt > 3) { bot += s3; top += l3; }
        res = (total - bot - top) / (dd * (float)tcnt);
    } else {
        res = total / (dd * dd);
    }
    out[idx] = res + hr2[idx];
}

// ---------------------------------------------------------------------------
extern "C" void kernel_launch(void* const* d_in, const int* in_sizes, int n_in,
                              void* d_out, int out_size, void* d_ws, size_t ws_size,
                              hipStream_t stream)
{
    const float* x   = (const float*)d_in[0];
    const int*   ei  = (const int*)d_in[1];
    const int    E   = in_sizes[1] / 2;
    const float* Wl0 = (const float*)d_in[2];
    const float* bl0 = (const float*)d_in[3];
    const float* Wr0 = (const float*)d_in[4];
    const float* br0 = (const float*)d_in[5];
    const float* g0  = (const float*)d_in[6];
    const float* be0 = (const float*)d_in[7];
    const float* Wl1 = (const float*)d_in[8];
    const float* bl1 = (const float*)d_in[9];
    const float* Wr1 = (const float*)d_in[10];
    const float* br1 = (const float*)d_in[11];
    const float* g1  = (const float*)d_in[12];
    const float* be1 = (const float*)d_in[13];
    const float* Wl2 = (const float*)d_in[14];
    const float* bl2 = (const float*)d_in[15];
    const float* Wr2 = (const float*)d_in[16];
    const float* br2 = (const float*)d_in[17];
    float* out = (float*)d_out;

    char* w = (char*)d_ws;
    int*      adj  = (int*)w;       w += (size_t)GN * MAXD * 4;
    int*      fill = (int*)w;       w += (size_t)GN * 4;
    _Float16* HL0  = (_Float16*)w;  w += (size_t)GN * 128 * 2;
    float*    HR0  = (float*)w;     w += (size_t)GN * 128 * 4;
    _Float16* HL1  = (_Float16*)w;  w += (size_t)GN * 128 * 2;
    float*    HR1  = (float*)w;     w += (size_t)GN * 128 * 4;
    short*    W5   = (short*)w;     w += (size_t)2 * 8192 * 16;
    float*    hl2  = (float*)w;     w += (size_t)GN * 2 * 4;
    float*    hr2  = (float*)w;     w += (size_t)GN * 2 * 4;

    k_prep  <<<GN / 256, 256, 0, stream>>>(fill, Wl0, Wr0, Wl1, Wr1, W5);
    k_fused0<<<576, 512, 0, stream>>>(x, ei, E, adj, fill, W5, bl0, br0, HL0, HR0);
    k_fused1<<<GN / 32, 512, 0, stream>>>(HL0, HR0, adj, fill, g0, be0,
                                          W5 + (size_t)8192 * 8, bl1, br1, HL1, HR1);
    k_fused2<<<GN / 4, 256, 0, stream>>>(HL1, HR1, adj, fill, g1, be1,
                                         Wl2, bl2, Wr2, br2, hl2, hr2);
    k_agg_out<<<GN * 2 / 256, 256, 0, stream>>>(hl2, hr2, adj, fill, out);
}